// Round 1
// baseline (10192.028 us; speedup 1.0000x reference)
//
#include <hip/hip_runtime.h>
#include <hip/hip_bf16.h>

#define NT 50
#define NB 512
#define SD 256
#define AD 32
#define BD 1024
#define HD 1024
#define ED 1024
#define MD 256

typedef __attribute__((ext_vector_type(8))) short bf16x8;
typedef __attribute__((ext_vector_type(4))) float f32x4;

__device__ __forceinline__ void gload_lds16(const void* g, void* l) {
  __builtin_amdgcn_global_load_lds(
      (const __attribute__((address_space(1))) void*)g,
      (__attribute__((address_space(3))) void*)l, 16, 0, 0);
}

__device__ __forceinline__ float sigmoidf_(float x) { return 1.0f / (1.0f + __expf(-x)); }
__device__ __forceinline__ float softplusf_(float x) {
  return (x > 0.0f) ? (x + log1pf(__expf(-x))) : log1pf(__expf(x));
}

// ---------------- GEMM: C = act(A @ W^T + bias) ----------------
// A: [M x K] bf16 row-major (lda elems), W: [N x K] bf16 row-major (ldw elems).
// Tile: BM=64 x BN=128, 4 waves in 2x2, each wave 32x64 (2x4 frags of 16x16), BK=32.
// LDS layout: 16B chunks, A: [kc(4)][row(64)], B: [kc(4)][col(128)] -- linear in
// global_load_lds lane order AND conflict-free on ds_read_b128 fragment reads.
// EPI: 0 = fp32 out (Cf), 1 = relu -> bf16 out (Cb).
template <int EPI>
__global__ __launch_bounds__(256) void gemm_nt(
    const __hip_bfloat16* __restrict__ A, int lda,
    const __hip_bfloat16* __restrict__ W, int ldw,
    const float* __restrict__ bias,
    float* __restrict__ Cf, __hip_bfloat16* __restrict__ Cb, int ldc, int K) {
  constexpr int BM = 64, BN = 128;
  __shared__ char lds[(4 * BM + 4 * BN) * 16];  // 12 KiB
  char* ldsA = lds;
  char* ldsB = lds + 4 * BM * 16;

  const int tid = threadIdx.x;
  const int lane = tid & 63;
  const int w = tid >> 6;          // wave 0..3
  const int wr = w >> 1, wc = w & 1;
  const int m0 = blockIdx.x * BM;
  const int n0 = blockIdx.y * BN;

  f32x4 acc[2][4] = {};

  const __hip_bfloat16* Arow = A + (size_t)(m0 + lane) * lda;        // per-lane row
  const __hip_bfloat16* Wrow0 = W + (size_t)(n0 + (w & 1) * 64 + lane) * ldw;

  for (int k0 = 0; k0 < K; k0 += 32) {
    __syncthreads();
    // stage A: wave w -> kc=w, rows=lane : 1 round (4 KiB)
    gload_lds16(Arow + k0 + w * 8, ldsA + w * 1024);
    // stage B: 2 rounds (8 KiB). round r: chunks r*256 + w*64 + lane
    // chunk = kc*128 + col : kc = 2r + (w>>1), col = (w&1)*64 + lane
    gload_lds16(Wrow0 + k0 + (w >> 1) * 8, ldsB + w * 1024);
    gload_lds16(Wrow0 + k0 + (2 + (w >> 1)) * 8, ldsB + 4096 + w * 1024);
    __syncthreads();

    const int kc = lane >> 4, r15 = lane & 15;
    bf16x8 af[2], bfr[4];
#pragma unroll
    for (int m = 0; m < 2; ++m)
      af[m] = *(const bf16x8*)(ldsA + (size_t)(kc * 64 + wr * 32 + m * 16 + r15) * 16);
#pragma unroll
    for (int n = 0; n < 4; ++n)
      bfr[n] = *(const bf16x8*)(ldsB + (size_t)(kc * 128 + wc * 64 + n * 16 + r15) * 16);
#pragma unroll
    for (int m = 0; m < 2; ++m)
#pragma unroll
      for (int n = 0; n < 4; ++n)
        acc[m][n] = __builtin_amdgcn_mfma_f32_16x16x32_bf16(af[m], bfr[n], acc[m][n], 0, 0, 0);
  }

  const int r15 = lane & 15, rg = lane >> 4;
#pragma unroll
  for (int m = 0; m < 2; ++m) {
#pragma unroll
    for (int n = 0; n < 4; ++n) {
      const int col = n0 + wc * 64 + n * 16 + r15;
      const float bv = bias[col];
#pragma unroll
      for (int i = 0; i < 4; ++i) {
        const int row = m0 + wr * 32 + m * 16 + rg * 4 + i;
        float v = acc[m][n][i] + bv;
        if (EPI == 1) {
          v = v > 0.0f ? v : 0.0f;
          Cb[(size_t)row * ldc + col] = __float2bfloat16(v);
        } else {
          Cf[(size_t)row * ldc + col] = v;
        }
      }
    }
  }
}

// ---------------- pointwise kernels ----------------

__global__ void cvt_f32_bf16(const float* __restrict__ src, __hip_bfloat16* __restrict__ dst, int n) {
  int i = blockIdx.x * 256 + threadIdx.x;
  if (i < n) dst[i] = __float2bfloat16(src[i]);
}

// xcat1[b, 0:544] = [qprev*nt | act | me]  (bf16)
__global__ void build_xcat1(const float* __restrict__ qprev, const float* __restrict__ nt_t,
                            const float* __restrict__ act_t, const float* __restrict__ me_t,
                            __hip_bfloat16* __restrict__ xcat1) {
  int i = blockIdx.x * 256 + threadIdx.x;
  if (i >= NB * 544) return;
  int b = i / 544, j = i - b * 544;
  float v;
  if (j < SD) v = qprev[b * SD + j] * nt_t[b];
  else if (j < SD + AD) v = act_t[b * AD + (j - SD)];
  else v = me_t[b * MD + (j - SD - AD)];
  xcat1[i] = __float2bfloat16(v);
}

// xcat2[b, 1024:2304] = [obs | mp]  (bf16); row stride 2304
__global__ void build_xcat2_om(const float* __restrict__ obs_t, const float* __restrict__ mp_t,
                               __hip_bfloat16* __restrict__ xcat2) {
  int i = blockIdx.x * 256 + threadIdx.x;
  if (i >= NB * 1280) return;
  int b = i / 1280, j = i - b * 1280;
  float v = (j < ED) ? obs_t[b * ED + j] : mp_t[b * MD + (j - ED)];
  xcat2[(size_t)b * 2304 + 1024 + j] = __float2bfloat16(v);
}

// xcat2[b, 0:1024] = bf16(prev_belief)
__global__ void init_belief(const float* __restrict__ prev_belief, __hip_bfloat16* __restrict__ xcat2) {
  int i = blockIdx.x * 256 + threadIdx.x;
  if (i >= NB * BD) return;
  int b = i >> 10, j = i & 1023;
  xcat2[(size_t)b * 2304 + j] = __float2bfloat16(prev_belief[i]);
}

// GRU pointwise: belief_out (fp32, into d_out) + bf16 belief into xcat2[:, :1024]
__global__ void gru_pw(const float* __restrict__ gi, const float* __restrict__ gh,
                       const float* __restrict__ hprev, float* __restrict__ bel_out,
                       __hip_bfloat16* __restrict__ xcat2) {
  int i = blockIdx.x * 256 + threadIdx.x;
  if (i >= NB * BD) return;
  int b = i >> 10, j = i & 1023;
  const float* gib = gi + (size_t)b * 3072;
  const float* ghb = gh + (size_t)b * 3072;
  float r = sigmoidf_(gib[j] + ghb[j]);
  float z = sigmoidf_(gib[j + 1024] + ghb[j + 1024]);
  float n = tanhf(gib[j + 2048] + r * ghb[j + 2048]);
  float h = hprev[i];
  float bel = (1.0f - z) * n + z * h;
  bel_out[i] = bel;
  xcat2[(size_t)b * 2304 + j] = __float2bfloat16(bel);
}

// prior/posterior heads: split mean/raw, std = min(softplus(raw)+0.1, 5), state = mean + std*noise
__global__ void pq_pw(const float* __restrict__ pout, const float* __restrict__ qout,
                      const float* __restrict__ np_t, const float* __restrict__ nq_t,
                      float* __restrict__ ps_o, float* __restrict__ pm_o, float* __restrict__ pd_o,
                      float* __restrict__ qs_o, float* __restrict__ qm_o, float* __restrict__ qd_o,
                      float* __restrict__ q_carry) {
  int i = blockIdx.x * 256 + threadIdx.x;
  if (i >= NB * SD) return;
  int b = i >> 8, j = i & 255;
  float pm = pout[(size_t)b * 512 + j];
  float pr = pout[(size_t)b * 512 + 256 + j];
  float pstd = fminf(softplusf_(pr) + 0.1f, 5.0f);
  float ps = pm + pstd * np_t[i];
  pm_o[i] = pm; pd_o[i] = pstd; ps_o[i] = ps;
  float qm = qout[(size_t)b * 512 + j];
  float qr = qout[(size_t)b * 512 + 256 + j];
  float qstd = fminf(softplusf_(qr) + 0.1f, 5.0f);
  float qs = qm + qstd * nq_t[i];
  qm_o[i] = qm; qd_o[i] = qstd; qs_o[i] = qs;
  q_carry[i] = qs;
}

// ---------------- host ----------------

extern "C" void kernel_launch(void* const* d_in, const int* in_sizes, int n_in,
                              void* d_out, int out_size, void* d_ws, size_t ws_size,
                              hipStream_t stream) {
  const float* prev_state   = (const float*)d_in[0];
  const float* actions      = (const float*)d_in[1];
  const float* prev_belief  = (const float*)d_in[2];
  const float* observations = (const float*)d_in[3];
  const float* nonterminals = (const float*)d_in[4];
  const float* me           = (const float*)d_in[5];
  const float* mp           = (const float*)d_in[6];
  const float* noise_p      = (const float*)d_in[7];
  const float* noise_q      = (const float*)d_in[8];
  const float* W_sa = (const float*)d_in[9];  const float* b_sa = (const float*)d_in[10];
  const float* W_ih = (const float*)d_in[11]; const float* b_ih = (const float*)d_in[12];
  const float* W_hh = (const float*)d_in[13]; const float* b_hh = (const float*)d_in[14];
  const float* W_bp = (const float*)d_in[15]; const float* b_bp = (const float*)d_in[16];
  const float* W_sp = (const float*)d_in[17]; const float* b_sp = (const float*)d_in[18];
  const float* W_bq = (const float*)d_in[19]; const float* b_bq = (const float*)d_in[20];
  const float* W_sq = (const float*)d_in[21]; const float* b_sq = (const float*)d_in[22];
  float* out = (float*)d_out;

  // ---- workspace carve (256B aligned) ----
  char* p = (char*)d_ws;
  auto carve = [&](size_t bytes) -> char* {
    char* r = p;
    p += (bytes + 255) & ~(size_t)255;
    return r;
  };
  __hip_bfloat16* Wsa_b = (__hip_bfloat16*)carve((size_t)BD * 544 * 2);
  __hip_bfloat16* Wih_b = (__hip_bfloat16*)carve((size_t)3 * BD * BD * 2);
  __hip_bfloat16* Whh_b = (__hip_bfloat16*)carve((size_t)3 * BD * BD * 2);
  __hip_bfloat16* Wbp_b = (__hip_bfloat16*)carve((size_t)HD * BD * 2);
  __hip_bfloat16* Wsp_b = (__hip_bfloat16*)carve((size_t)2 * SD * HD * 2);
  __hip_bfloat16* Wbq_b = (__hip_bfloat16*)carve((size_t)HD * 2304 * 2);
  __hip_bfloat16* Wsq_b = (__hip_bfloat16*)carve((size_t)2 * SD * HD * 2);
  __hip_bfloat16* xcat1 = (__hip_bfloat16*)carve((size_t)NB * 544 * 2);
  __hip_bfloat16* xcat2 = (__hip_bfloat16*)carve((size_t)NB * 2304 * 2);
  __hip_bfloat16* hid_b = (__hip_bfloat16*)carve((size_t)NB * BD * 2);
  __hip_bfloat16* hp_b  = (__hip_bfloat16*)carve((size_t)NB * HD * 2);
  __hip_bfloat16* hq_b  = (__hip_bfloat16*)carve((size_t)NB * HD * 2);
  float* gi_f   = (float*)carve((size_t)NB * 3 * BD * 4);
  float* gh_f   = (float*)carve((size_t)NB * 3 * BD * 4);
  float* pout_f = (float*)carve((size_t)NB * 512 * 4);
  float* qout_f = (float*)carve((size_t)NB * 512 * 4);
  float* q_carry = (float*)carve((size_t)NB * SD * 4);

  // ---- convert weights to bf16 (each call; cheap) ----
  auto cvt = [&](const float* s, __hip_bfloat16* d, int n) {
    cvt_f32_bf16<<<(n + 255) / 256, 256, 0, stream>>>(s, d, n);
  };
  cvt(W_sa, Wsa_b, BD * 544);
  cvt(W_ih, Wih_b, 3 * BD * BD);
  cvt(W_hh, Whh_b, 3 * BD * BD);
  cvt(W_bp, Wbp_b, HD * BD);
  cvt(W_sp, Wsp_b, 2 * SD * HD);
  cvt(W_bq, Wbq_b, HD * 2304);
  cvt(W_sq, Wsq_b, 2 * SD * HD);
  init_belief<<<(NB * BD + 255) / 256, 256, 0, stream>>>(prev_belief, xcat2);

  const size_t o_ps = (size_t)NT * NB * BD;       // start of p_state block
  const size_t blk  = (size_t)NT * NB * SD;       // size of each S-dim output block

  for (int t = 0; t < NT; ++t) {
    const float* nt_t  = nonterminals + (size_t)t * NB;
    const float* act_t = actions + (size_t)t * NB * AD;
    const float* me_t  = me + (size_t)t * NB * MD;
    const float* obs_t = observations + (size_t)t * NB * ED;
    const float* mp_t  = mp + (size_t)t * NB * MD;
    const float* np_t  = noise_p + (size_t)t * NB * SD;
    const float* nq_t  = noise_q + (size_t)t * NB * SD;
    float* out_bel = out + (size_t)t * NB * BD;
    const float* hprev = (t == 0) ? prev_belief : (out + (size_t)(t - 1) * NB * BD);
    const float* qprev = (t == 0) ? prev_state : q_carry;

    // 1) xcat1 = [q_prev*nt | a | me]
    build_xcat1<<<(NB * 544 + 255) / 256, 256, 0, stream>>>(qprev, nt_t, act_t, me_t, xcat1);
    // 2) hid = relu(xcat1 @ W_sa^T + b_sa) -> bf16
    gemm_nt<1><<<dim3(NB / 64, BD / 128), 256, 0, stream>>>(xcat1, 544, Wsa_b, 544, b_sa,
                                                            nullptr, hid_b, BD, 544);
    // 3) gi = hid @ W_ih^T + b_ih (fp32)
    gemm_nt<0><<<dim3(NB / 64, 3 * BD / 128), 256, 0, stream>>>(hid_b, BD, Wih_b, BD, b_ih,
                                                                gi_f, nullptr, 3 * BD, BD);
    // 4) gh = belief_{t-1} @ W_hh^T + b_hh (belief lives in xcat2[:, :1024], stride 2304)
    gemm_nt<0><<<dim3(NB / 64, 3 * BD / 128), 256, 0, stream>>>(xcat2, 2304, Whh_b, BD, b_hh,
                                                                gh_f, nullptr, 3 * BD, BD);
    // 5) GRU -> belief fp32 (d_out) + bf16 (xcat2[:, :1024])
    gru_pw<<<(NB * BD + 255) / 256, 256, 0, stream>>>(gi_f, gh_f, hprev, out_bel, xcat2);
    // 6) xcat2[:, 1024:2304] = [obs | mp]
    build_xcat2_om<<<(NB * 1280 + 255) / 256, 256, 0, stream>>>(obs_t, mp_t, xcat2);
    // 7) hp = relu(belief @ W_bp^T + b_bp) -> bf16
    gemm_nt<1><<<dim3(NB / 64, HD / 128), 256, 0, stream>>>(xcat2, 2304, Wbp_b, BD, b_bp,
                                                            nullptr, hp_b, HD, BD);
    // 8) hq = relu(xcat2 @ W_bq^T + b_bq) -> bf16
    gemm_nt<1><<<dim3(NB / 64, HD / 128), 256, 0, stream>>>(xcat2, 2304, Wbq_b, 2304, b_bq,
                                                            nullptr, hq_b, HD, 2304);
    // 9) pout = hp @ W_sp^T + b_sp (fp32)
    gemm_nt<0><<<dim3(NB / 64, 512 / 128), 256, 0, stream>>>(hp_b, HD, Wsp_b, HD, b_sp,
                                                             pout_f, nullptr, 512, HD);
    // 10) qout = hq @ W_sq^T + b_sq (fp32)
    gemm_nt<0><<<dim3(NB / 64, 512 / 128), 256, 0, stream>>>(hq_b, HD, Wsq_b, HD, b_sq,
                                                             qout_f, nullptr, 512, HD);
    // 11) heads
    pq_pw<<<(NB * SD + 255) / 256, 256, 0, stream>>>(
        pout_f, qout_f, np_t, nq_t,
        out + o_ps + (size_t)t * NB * SD,            // p_state
        out + o_ps + blk + (size_t)t * NB * SD,      // p_mean
        out + o_ps + 2 * blk + (size_t)t * NB * SD,  // p_std
        out + o_ps + 3 * blk + (size_t)t * NB * SD,  // q_state
        out + o_ps + 4 * blk + (size_t)t * NB * SD,  // q_mean
        out + o_ps + 5 * blk + (size_t)t * NB * SD,  // q_std
        q_carry);
  }
}

// Round 2
// 5693.576 us; speedup vs baseline: 1.7901x; 1.7901x over previous
//
#include <hip/hip_runtime.h>
#include <hip/hip_bf16.h>

#define NT 50
#define NB 512
#define SD 256
#define AD 32
#define BD 1024
#define HD 1024
#define ED 1024
#define MD 256

typedef __attribute__((ext_vector_type(8))) short bf16x8;
typedef __attribute__((ext_vector_type(4))) float f32x4;

__device__ __forceinline__ void gload_lds16(const void* g, void* l) {
  __builtin_amdgcn_global_load_lds(
      (const __attribute__((address_space(1))) void*)g,
      (__attribute__((address_space(3))) void*)l, 16, 0, 0);
}

__device__ __forceinline__ float sigmoidf_(float x) { return 1.0f / (1.0f + __expf(-x)); }
__device__ __forceinline__ float softplusf_(float x) {
  return (x > 0.0f) ? (x + log1pf(__expf(-x))) : log1pf(__expf(x));
}

// ---------------- GEMM descriptors ----------------
struct GDesc {
  const __hip_bfloat16* A1; const __hip_bfloat16* A2;  // A2 for K-range [K1, K)
  int lda1, lda2, K1, K;
  const __hip_bfloat16* W; int ldw;
  const float* bias;
  float* Cf; __hip_bfloat16* Cb; int ldc;
};

// ---------------- generic GEMM: C = act(A @ W^T + bias) ----------------
// Tile BM=64 x BN=64, 4 waves (2x2), each 32x32 (2x2 frags), BK=32,
// double-buffered LDS (2-phase prefetch). LDS 16B-chunk layout:
// A: [kc(4)][row(64)], B: [kc(4)][col(64)] per buffer.
// EPI: 0 = fp32 out, 1 = relu -> bf16 out.
template <int EPI>
__global__ __launch_bounds__(256) void gemm_bt(GDesc d0, GDesc d1) {
  const GDesc d = (blockIdx.z == 0) ? d0 : d1;
  __shared__ alignas(16) char lds[16384];  // 2 bufs x (4KB A + 4KB B)

  const int tid = threadIdx.x;
  const int lane = tid & 63;
  const int w = tid >> 6;
  const int wr = w >> 1, wc = w & 1;
  const int m0 = blockIdx.x * 64;
  const int n0 = blockIdx.y * 64;

  f32x4 acc[2][2] = {};

  const __hip_bfloat16* a1row = d.A1 + (size_t)(m0 + lane) * d.lda1;
  const __hip_bfloat16* a2row = d.A2 ? d.A2 + (size_t)(m0 + lane) * d.lda2 : nullptr;
  const __hip_bfloat16* wrow = d.W + (size_t)(n0 + lane) * d.ldw;

  auto stage = [&](int buf, int k0) {
    char* la = lds + buf * 8192;
    char* lb = la + 4096;
    const __hip_bfloat16* as =
        (k0 < d.K1) ? (a1row + k0) : (a2row + (k0 - d.K1));
    gload_lds16(as + w * 8, la + w * 1024);           // A chunk kc=w, row=lane
    gload_lds16(wrow + k0 + w * 8, lb + w * 1024);    // B chunk kc=w, col=lane
  };

  stage(0, 0);
  int cur = 0;
  const int kc = lane >> 4, r15 = lane & 15;
  for (int k0 = 0;; k0 += 32) {
    __syncthreads();                       // stage(cur) complete; prev reads done
    if (k0 + 32 < d.K) stage(cur ^ 1, k0 + 32);
    const char* la = lds + cur * 8192;
    const char* lb = la + 4096;
    bf16x8 af[2], bfr[2];
#pragma unroll
    for (int m = 0; m < 2; ++m)
      af[m] = *(const bf16x8*)(la + (size_t)(kc * 64 + wr * 32 + m * 16 + r15) * 16);
#pragma unroll
    for (int n = 0; n < 2; ++n)
      bfr[n] = *(const bf16x8*)(lb + (size_t)(kc * 64 + wc * 32 + n * 16 + r15) * 16);
#pragma unroll
    for (int m = 0; m < 2; ++m)
#pragma unroll
      for (int n = 0; n < 2; ++n)
        acc[m][n] = __builtin_amdgcn_mfma_f32_16x16x32_bf16(af[m], bfr[n], acc[m][n], 0, 0, 0);
    cur ^= 1;
    if (k0 + 32 >= d.K) break;
  }

  const int rg = lane >> 4;
#pragma unroll
  for (int m = 0; m < 2; ++m) {
#pragma unroll
    for (int n = 0; n < 2; ++n) {
      const int col = n0 + wc * 32 + n * 16 + r15;
      const float bv = d.bias[col];
#pragma unroll
      for (int i = 0; i < 4; ++i) {
        const int row = m0 + wr * 32 + m * 16 + rg * 4 + i;
        float v = acc[m][n][i] + bv;
        if (EPI == 1) {
          v = v > 0.0f ? v : 0.0f;
          d.Cb[(size_t)row * d.ldc + col] = __float2bfloat16(v);
        } else {
          d.Cf[(size_t)row * d.ldc + col] = v;
        }
      }
    }
  }
}

// ---------------- head GEMM with fused prior/posterior epilogue ----------------
// W rows pre-interleaved: out col 2j = mean_j, 2j+1 = raw_j. K=1024, N=512.
struct HDesc {
  const __hip_bfloat16* A; const __hip_bfloat16* W;
  const float* bias; const float* noise;
  float* st_o; float* mn_o; float* sd_o;
};

__global__ __launch_bounds__(256) void gemm_head(
    HDesc h0, HDesc h1, const float* __restrict__ ntn,
    __hip_bfloat16* __restrict__ sprev_b) {
  const HDesc h = (blockIdx.z == 0) ? h0 : h1;
  const bool isq = (blockIdx.z == 1);
  __shared__ alignas(16) char lds[16384];

  const int tid = threadIdx.x;
  const int lane = tid & 63;
  const int w = tid >> 6;
  const int wr = w >> 1, wc = w & 1;
  const int m0 = blockIdx.x * 64;
  const int n0 = blockIdx.y * 64;

  f32x4 acc[2][2] = {};
  const __hip_bfloat16* arow = h.A + (size_t)(m0 + lane) * HD;
  const __hip_bfloat16* wrow = h.W + (size_t)(n0 + lane) * HD;

  auto stage = [&](int buf, int k0) {
    char* la = lds + buf * 8192;
    gload_lds16(arow + k0 + w * 8, la + w * 1024);
    gload_lds16(wrow + k0 + w * 8, la + 4096 + w * 1024);
  };

  stage(0, 0);
  int cur = 0;
  const int kc = lane >> 4, r15 = lane & 15;
  for (int k0 = 0;; k0 += 32) {
    __syncthreads();
    if (k0 + 32 < HD) stage(cur ^ 1, k0 + 32);
    const char* la = lds + cur * 8192;
    const char* lb = la + 4096;
    bf16x8 af[2], bfr[2];
#pragma unroll
    for (int m = 0; m < 2; ++m)
      af[m] = *(const bf16x8*)(la + (size_t)(kc * 64 + wr * 32 + m * 16 + r15) * 16);
#pragma unroll
    for (int n = 0; n < 2; ++n)
      bfr[n] = *(const bf16x8*)(lb + (size_t)(kc * 64 + wc * 32 + n * 16 + r15) * 16);
#pragma unroll
    for (int m = 0; m < 2; ++m)
#pragma unroll
      for (int n = 0; n < 2; ++n)
        acc[m][n] = __builtin_amdgcn_mfma_f32_16x16x32_bf16(af[m], bfr[n], acc[m][n], 0, 0, 0);
    cur ^= 1;
    if (k0 + 32 >= HD) break;
  }

  const int rg = lane >> 4;
  const bool even = (r15 & 1) == 0;
#pragma unroll
  for (int m = 0; m < 2; ++m) {
#pragma unroll
    for (int n = 0; n < 2; ++n) {
      const int col = n0 + wc * 32 + n * 16 + r15;   // 0..511 interleaved
      const int j = col >> 1;
      const float bv = h.bias[col];
#pragma unroll
      for (int i = 0; i < 4; ++i) {
        const int row = m0 + wr * 32 + m * 16 + rg * 4 + i;
        float v = acc[m][n][i] + bv;
        float partner = __shfl_xor(v, 1);
        float mean = even ? v : partner;
        float raw = even ? partner : v;
        float sd = fminf(softplusf_(raw) + 0.1f, 5.0f);
        const size_t o = (size_t)row * SD + j;
        if (even) {
          float st = mean + sd * h.noise[o];
          h.mn_o[o] = mean;
          h.st_o[o] = st;
          if (isq) sprev_b[o] = __float2bfloat16(st * ntn[row]);
        } else {
          h.sd_o[o] = sd;
        }
      }
    }
  }
}

// ---------------- pointwise / prep kernels ----------------

__global__ void cvt_f32_bf16(const float* __restrict__ src, __hip_bfloat16* __restrict__ dst, int n) {
  int i = blockIdx.x * 256 + threadIdx.x;
  if (i < n) dst[i] = __float2bfloat16(src[i]);
}

// reorder W (512 x 1024): src row j<256 -> dst row 2j (mean), j>=256 -> 2(j-256)+1 (raw)
__global__ void cvt_reorder_w(const float* __restrict__ src, __hip_bfloat16* __restrict__ dst) {
  int i = blockIdx.x * 256 + threadIdx.x;
  if (i >= 512 * 1024) return;
  int r = i >> 10, k = i & 1023;
  int dr = (r < 256) ? (2 * r) : (2 * (r - 256) + 1);
  dst[(size_t)dr * 1024 + k] = __float2bfloat16(src[i]);
}

__global__ void reorder_bias(const float* __restrict__ src, float* __restrict__ dst) {
  int i = blockIdx.x * 256 + threadIdx.x;
  if (i >= 512) return;
  int dr = (i < 256) ? (2 * i) : (2 * (i - 256) + 1);
  dst[dr] = src[i];
}

// actme_b[t][b][0:288] = [act | me] bf16
__global__ void build_actme(const float* __restrict__ act, const float* __restrict__ me,
                            __hip_bfloat16* __restrict__ dst) {
  int i = blockIdx.x * 256 + threadIdx.x;
  if (i >= NT * NB * 288) return;
  int tb = i / 288, j = i - tb * 288;
  float v = (j < AD) ? act[(size_t)tb * AD + j] : me[(size_t)tb * MD + (j - AD)];
  dst[i] = __float2bfloat16(v);
}

// t=0 init: sprev_b = bf16(prev_state*nt0), bel_b = bf16(prev_belief)
__global__ void init_state(const float* __restrict__ prev_state, const float* __restrict__ nt0,
                           const float* __restrict__ prev_belief,
                           __hip_bfloat16* __restrict__ sprev_b, __hip_bfloat16* __restrict__ bel_b) {
  int i = blockIdx.x * 256 + threadIdx.x;
  if (i >= NB * 1280) return;
  int b = i / 1280, j = i - b * 1280;
  if (j < SD) sprev_b[b * SD + j] = __float2bfloat16(prev_state[b * SD + j] * nt0[b]);
  else bel_b[(size_t)b * BD + (j - SD)] = __float2bfloat16(prev_belief[(size_t)b * BD + (j - SD)]);
}

// GRU pointwise + obs/mp bf16 build (independent halves, one dispatch)
__global__ void gru_obs(const float* __restrict__ gi, const float* __restrict__ gh,
                        const float* __restrict__ hprev,
                        const float* __restrict__ obs_t, const float* __restrict__ mp_t,
                        float* __restrict__ bel_out, __hip_bfloat16* __restrict__ bel_b,
                        __hip_bfloat16* __restrict__ obsmp_b) {
  int i = blockIdx.x * 256 + threadIdx.x;
  if (i >= NB * 2304) return;
  int b = i / 2304, j = i - b * 2304;
  if (j < BD) {
    const float* gib = gi + (size_t)b * 3072;
    const float* ghb = gh + (size_t)b * 3072;
    float r = sigmoidf_(gib[j] + ghb[j]);
    float z = sigmoidf_(gib[j + 1024] + ghb[j + 1024]);
    float n = tanhf(gib[j + 2048] + r * ghb[j + 2048]);
    float hv = hprev[(size_t)b * BD + j];
    float bel = (1.0f - z) * n + z * hv;
    bel_out[(size_t)b * BD + j] = bel;
    bel_b[(size_t)b * BD + j] = __float2bfloat16(bel);
  } else {
    int jj = j - BD;
    float v = (jj < ED) ? obs_t[(size_t)b * ED + jj] : mp_t[(size_t)b * MD + (jj - ED)];
    obsmp_b[(size_t)b * 1280 + jj] = __float2bfloat16(v);
  }
}

// ---------------- host ----------------

extern "C" void kernel_launch(void* const* d_in, const int* in_sizes, int n_in,
                              void* d_out, int out_size, void* d_ws, size_t ws_size,
                              hipStream_t stream) {
  const float* prev_state   = (const float*)d_in[0];
  const float* actions      = (const float*)d_in[1];
  const float* prev_belief  = (const float*)d_in[2];
  const float* observations = (const float*)d_in[3];
  const float* nonterminals = (const float*)d_in[4];
  const float* me           = (const float*)d_in[5];
  const float* mp           = (const float*)d_in[6];
  const float* noise_p      = (const float*)d_in[7];
  const float* noise_q      = (const float*)d_in[8];
  const float* W_sa = (const float*)d_in[9];  const float* b_sa = (const float*)d_in[10];
  const float* W_ih = (const float*)d_in[11]; const float* b_ih = (const float*)d_in[12];
  const float* W_hh = (const float*)d_in[13]; const float* b_hh = (const float*)d_in[14];
  const float* W_bp = (const float*)d_in[15]; const float* b_bp = (const float*)d_in[16];
  const float* W_sp = (const float*)d_in[17]; const float* b_sp = (const float*)d_in[18];
  const float* W_bq = (const float*)d_in[19]; const float* b_bq = (const float*)d_in[20];
  const float* W_sq = (const float*)d_in[21]; const float* b_sq = (const float*)d_in[22];
  float* out = (float*)d_out;

  char* p = (char*)d_ws;
  auto carve = [&](size_t bytes) -> char* {
    char* r = p;
    p += (bytes + 255) & ~(size_t)255;
    return r;
  };
  __hip_bfloat16* Wsa_b  = (__hip_bfloat16*)carve((size_t)BD * 544 * 2);
  __hip_bfloat16* Wih_b  = (__hip_bfloat16*)carve((size_t)3 * BD * BD * 2);
  __hip_bfloat16* Whh_b  = (__hip_bfloat16*)carve((size_t)3 * BD * BD * 2);
  __hip_bfloat16* Wbp_b  = (__hip_bfloat16*)carve((size_t)HD * BD * 2);
  __hip_bfloat16* Wsp_ro = (__hip_bfloat16*)carve((size_t)512 * HD * 2);
  __hip_bfloat16* Wbq_b  = (__hip_bfloat16*)carve((size_t)HD * 2304 * 2);
  __hip_bfloat16* Wsq_ro = (__hip_bfloat16*)carve((size_t)512 * HD * 2);
  float* bsp_ro = (float*)carve(512 * 4);
  float* bsq_ro = (float*)carve(512 * 4);
  __hip_bfloat16* actme_b = (__hip_bfloat16*)carve((size_t)NT * NB * 288 * 2);
  __hip_bfloat16* obsmp_b = (__hip_bfloat16*)carve((size_t)NB * 1280 * 2);
  __hip_bfloat16* sprev_b = (__hip_bfloat16*)carve((size_t)NB * SD * 2);
  __hip_bfloat16* bel_b   = (__hip_bfloat16*)carve((size_t)NB * BD * 2);
  __hip_bfloat16* hid_b   = (__hip_bfloat16*)carve((size_t)NB * BD * 2);
  __hip_bfloat16* hp_b    = (__hip_bfloat16*)carve((size_t)NB * HD * 2);
  __hip_bfloat16* hq_b    = (__hip_bfloat16*)carve((size_t)NB * HD * 2);
  float* gi_f = (float*)carve((size_t)NB * 3 * BD * 4);
  float* gh_f = (float*)carve((size_t)NB * 3 * BD * 4);

  auto cvt = [&](const float* s, __hip_bfloat16* d, int n) {
    cvt_f32_bf16<<<(n + 255) / 256, 256, 0, stream>>>(s, d, n);
  };
  cvt(W_sa, Wsa_b, BD * 544);
  cvt(W_ih, Wih_b, 3 * BD * BD);
  cvt(W_hh, Whh_b, 3 * BD * BD);
  cvt(W_bp, Wbp_b, HD * BD);
  cvt(W_bq, Wbq_b, HD * 2304);
  cvt_reorder_w<<<(512 * 1024 + 255) / 256, 256, 0, stream>>>(W_sp, Wsp_ro);
  cvt_reorder_w<<<(512 * 1024 + 255) / 256, 256, 0, stream>>>(W_sq, Wsq_ro);
  reorder_bias<<<2, 256, 0, stream>>>(b_sp, bsp_ro);
  reorder_bias<<<2, 256, 0, stream>>>(b_sq, bsq_ro);
  build_actme<<<(NT * NB * 288 + 255) / 256, 256, 0, stream>>>(actions, me, actme_b);
  init_state<<<(NB * 1280 + 255) / 256, 256, 0, stream>>>(prev_state, nonterminals,
                                                          prev_belief, sprev_b, bel_b);

  const size_t o_ps = (size_t)NT * NB * BD;
  const size_t blk  = (size_t)NT * NB * SD;

  for (int t = 0; t < NT; ++t) {
    const float* obs_t = observations + (size_t)t * NB * ED;
    const float* mp_t  = mp + (size_t)t * NB * MD;
    const float* np_t  = noise_p + (size_t)t * NB * SD;
    const float* nq_t  = noise_q + (size_t)t * NB * SD;
    float* out_bel = out + (size_t)t * NB * BD;
    const float* hprev = (t == 0) ? prev_belief : (out + (size_t)(t - 1) * NB * BD);
    const float* ntn = nonterminals + (size_t)((t + 1 < NT) ? t + 1 : t) * NB;

    // 1) hid = relu([sprev | actme_t] @ W_sa^T + b_sa)  (K = 256 + 288)
    {
      GDesc d{sprev_b, actme_b + (size_t)t * NB * 288, SD, 288, SD, 544,
              Wsa_b, 544, b_sa, nullptr, hid_b, BD};
      gemm_bt<1><<<dim3(8, 16, 1), 256, 0, stream>>>(d, d);
    }
    // 2) gi = hid @ W_ih^T + b_ih ; gh = belief @ W_hh^T + b_hh  (z-merged)
    {
      GDesc di{hid_b, nullptr, BD, 0, BD, BD, Wih_b, BD, b_ih, gi_f, nullptr, 3 * BD};
      GDesc dh{bel_b, nullptr, BD, 0, BD, BD, Whh_b, BD, b_hh, gh_f, nullptr, 3 * BD};
      gemm_bt<0><<<dim3(8, 48, 2), 256, 0, stream>>>(di, dh);
    }
    // 3) GRU pointwise (belief -> d_out fp32 + bel_b bf16) + obs/mp bf16 build
    gru_obs<<<(NB * 2304 + 255) / 256, 256, 0, stream>>>(gi_f, gh_f, hprev, obs_t, mp_t,
                                                         out_bel, bel_b, obsmp_b);
    // 4) hp = relu(bel @ W_bp^T) ; hq = relu([bel | obsmp] @ W_bq^T)  (z-merged)
    {
      GDesc dp{bel_b, nullptr, BD, 0, BD, BD, Wbp_b, BD, b_bp, nullptr, hp_b, HD};
      GDesc dq{bel_b, obsmp_b, BD, 1280, BD, 2304, Wbq_b, 2304, b_bq, nullptr, hq_b, HD};
      gemm_bt<1><<<dim3(8, 16, 2), 256, 0, stream>>>(dp, dq);
    }
    // 5) p/q heads: GEMM + fused softplus/state epilogue + next-step sprev carry
    {
      HDesc hp_{hp_b, Wsp_ro, bsp_ro, np_t,
                out + o_ps + (size_t)t * NB * SD,
                out + o_ps + blk + (size_t)t * NB * SD,
                out + o_ps + 2 * blk + (size_t)t * NB * SD};
      HDesc hq_{hq_b, Wsq_ro, bsq_ro, nq_t,
                out + o_ps + 3 * blk + (size_t)t * NB * SD,
                out + o_ps + 4 * blk + (size_t)t * NB * SD,
                out + o_ps + 5 * blk + (size_t)t * NB * SD};
      gemm_head<<<dim3(8, 8, 2), 256, 0, stream>>>(hp_, hq_, ntn, sprev_b);
    }
  }
}